// Round 5
// baseline (43.421 us; speedup 1.0000x reference)
//
#include <hip/hip_runtime.h>
#include <math.h>

#define NPTS 4096
#define NBATCH 8

// ws layout (float offsets):
//   [0, 32)    centroid: 4 floats per batch (x,y,z,pad)
//   [32, 800)  fused coeffs: A0,A1,A2,vd,vl,beff each [128]
#define WS_CENT 0
#define WS_COEF 32

// blocks 0..7: centroid per batch; block 8: coeff fold.
__launch_bounds__(256)
__global__ void prep_kernel(const float* __restrict__ pts,
                            const float* __restrict__ W_rel, const float* __restrict__ b_rel,
                            const float* __restrict__ W_dist, const float* __restrict__ b_dist,
                            const float* __restrict__ W_dens, const float* __restrict__ b_dens,
                            const float* __restrict__ W_out, const float* __restrict__ b_out,
                            float* __restrict__ ws) {
    __shared__ float sx[256], sy[256], sz[256];
    if (blockIdx.x < NBATCH) {
        int b = blockIdx.x;
        const float* P = pts + (size_t)b * NPTS * 3;
        float ax = 0.f, ay = 0.f, az = 0.f;
        for (int n = threadIdx.x; n < NPTS; n += 256) {
            ax += P[3 * n + 0];
            ay += P[3 * n + 1];
            az += P[3 * n + 2];
        }
        sx[threadIdx.x] = ax; sy[threadIdx.x] = ay; sz[threadIdx.x] = az;
        __syncthreads();
        for (int off = 128; off > 0; off >>= 1) {
            if (threadIdx.x < off) {
                sx[threadIdx.x] += sx[threadIdx.x + off];
                sy[threadIdx.x] += sy[threadIdx.x + off];
                sz[threadIdx.x] += sz[threadIdx.x + off];
            }
            __syncthreads();
        }
        if (threadIdx.x == 0) {
            const float inv = 1.0f / (float)NPTS;
            ws[WS_CENT + 4 * b + 0] = sx[0] * inv;
            ws[WS_CENT + 4 * b + 1] = sy[0] * inv;
            ws[WS_CENT + 4 * b + 2] = sz[0] * inv;
        }
    } else if (threadIdx.x < 128) {
        int o = threadIdx.x;
        float a0 = 0.f, a1 = 0.f, a2 = 0.f, vd = 0.f, vl = 0.f, be = b_out[o];
        for (int j = 0; j < 42; ++j) {
            float w0 = W_out[j * 128 + o];
            float w1 = W_out[(42 + j) * 128 + o];
            float w2 = W_out[(84 + j) * 128 + o];
            a0 = fmaf(W_rel[j],      w0, a0);
            a1 = fmaf(W_rel[42 + j], w0, a1);
            a2 = fmaf(W_rel[84 + j], w0, a2);
            vd = fmaf(W_dist[j],     w1, vd);
            vl = fmaf(W_dens[j],     w2, vl);
            be = fmaf(b_rel[j],  w0, be);
            be = fmaf(b_dist[j], w1, be);
            be = fmaf(b_dens[j], w2, be);
        }
        float* C = ws + WS_COEF;
        C[0 * 128 + o] = a0; C[1 * 128 + o] = a1; C[2 * 128 + o] = a2;
        C[3 * 128 + o] = vd; C[4 * 128 + o] = vl; C[5 * 128 + o] = be;
    }
}

// 3-op sorted-triple insert via med3 (rank-k insert identity). Keeps t0<=t1<=t2.
#define INS3(t0, t1, t2, v)                                   \
    {                                                         \
        float n0 = fminf(t0, (v));                            \
        float n1 = __builtin_amdgcn_fmed3f(t0, t1, (v));      \
        float n2 = __builtin_amdgcn_fmed3f(t1, t2, (v));      \
        t0 = n0; t1 = n1; t2 = n2;                            \
    }

// Merge partner's sorted triple (7 min/max) via xor-butterfly step.
#define MERGE3(t0, t1, t2, m)                                 \
    {                                                         \
        float b0 = __shfl_xor(t0, m);                         \
        float b1 = __shfl_xor(t1, m);                         \
        float b2 = __shfl_xor(t2, m);                         \
        float X = fmaxf(t0, b0);                              \
        t0 = fminf(t0, b0);                                   \
        float Y = fminf(t1, b1);                              \
        float Z = fmaxf(X, Y);                                \
        t1 = fminf(X, Y);                                     \
        t2 = fminf(Z, fminf(t2, b2));                         \
    }

#define RFL(x) __uint_as_float(__builtin_amdgcn_readfirstlane(__float_as_uint(x)))

// Query j of this wave lives at lp4s[j][g*8+w]. Coefs forced to SGPRs.
#define DECLQ(j)                                              \
    float4 Q##j = lp4s[j][qrow];                              \
    float qx##j = RFL(-2.0f * Q##j.x);                        \
    float qy##j = RFL(-2.0f * Q##j.y);                        \
    float qz##j = RFL(-2.0f * Q##j.z);                        \
    float sq##j = RFL(Q##j.w);                                \
    float t##j##0 = INFINITY, t##j##1 = INFINITY, t##j##2 = INFINITY;

#define STEP(j)                                                             \
    {                                                                       \
        float e = fmaf(qx##j, c.x, fmaf(qy##j, c.y, fmaf(qz##j, c.z, c.w)));\
        INS3(t##j##0, t##j##1, t##j##2, e);                                 \
    }

// self's e = -|p|^2 is the strict minimum on its lane -> shift triple there.
#define SELF(j)                                                             \
    if (lane == ((w << 3) + j)) {                                           \
        t##j##0 = t##j##1; t##j##1 = t##j##2; t##j##2 = INFINITY;           \
    }

#define MRG(j, m) MERGE3(t##j##0, t##j##1, t##j##2, m)

#define DENS(j)                                                             \
    float d##j = (sqrtf(fmaxf(t##j##0 + sq##j, 1e-12f)) +                   \
                  sqrtf(fmaxf(t##j##1 + sq##j, 1e-12f)) +                   \
                  sqrtf(fmaxf(t##j##2 + sq##j, 1e-12f))) * (1.0f / 3.0f);

// 512 blocks x 512 thr (8 waves): block owns 64 queries of one batch, wave owns
// 8 (coefs in SGPR), lanes hold candidates (1 ds_read_b128 -> 64 cand x 8 q).
// Points in 8 padded sub-arrays lp4s[8][513]: point m -> lp4s[m&7][m>>3].
// Staging writes lane-contiguous (conflict-free); scan reads 8x128B chunks at
// 513-stride offsets (bank-balanced). 66 KB LDS -> 2 blocks/CU for overlap.
__launch_bounds__(512, 4)
__global__ void density_out_kernel(const float* __restrict__ pts,
                                   const float* __restrict__ ws,
                                   float* __restrict__ out) {
    __shared__ float4 lp4s[8][513];
    __shared__ float dens[64];
    int b = blockIdx.x >> 6;
    int g = blockIdx.x & 63;
    int tid = threadIdx.x;
    int w = tid >> 6, lane = tid & 63;

    // ---- stage: thread t loads points 8t..8t+7 (6 coalesced float4 loads),
    //      writes lp4s[j][t] (lane-contiguous, conflict-free) ----
    {
        const float4* P4 = (const float4*)(pts + (size_t)b * NPTS * 3);
        float4 v0 = P4[6 * tid + 0];
        float4 v1 = P4[6 * tid + 1];
        float4 v2 = P4[6 * tid + 2];
        float4 v3 = P4[6 * tid + 3];
        float4 v4 = P4[6 * tid + 4];
        float4 v5 = P4[6 * tid + 5];
        #define SQ4(x, y, z) make_float4((x), (y), (z), fmaf((x), (x), fmaf((y), (y), (z) * (z))))
        lp4s[0][tid] = SQ4(v0.x, v0.y, v0.z);
        lp4s[1][tid] = SQ4(v0.w, v1.x, v1.y);
        lp4s[2][tid] = SQ4(v1.z, v1.w, v2.x);
        lp4s[3][tid] = SQ4(v2.y, v2.z, v2.w);
        lp4s[4][tid] = SQ4(v3.x, v3.y, v3.z);
        lp4s[5][tid] = SQ4(v3.w, v4.x, v4.y);
        lp4s[6][tid] = SQ4(v4.z, v4.w, v5.x);
        lp4s[7][tid] = SQ4(v5.y, v5.z, v5.w);
        #undef SQ4
    }
    __syncthreads();

    // ---- scan: 8 queries/wave; lane reads candidate (tile*64+lane) ----
    int qrow = (g << 3) + w;  // queries (g*64 + w*8 + j) -> lp4s[j][g*8+w]
    DECLQ(0) DECLQ(1) DECLQ(2) DECLQ(3) DECLQ(4) DECLQ(5) DECLQ(6) DECLQ(7)

    const float4* cbase = &lp4s[lane & 7][lane >> 3];
    #pragma unroll 4
    for (int tile = 0; tile < 64; ++tile) {
        float4 c = cbase[tile << 3];
        STEP(0) STEP(1) STEP(2) STEP(3) STEP(4) STEP(5) STEP(6) STEP(7)
    }

    SELF(0) SELF(1) SELF(2) SELF(3) SELF(4) SELF(5) SELF(6) SELF(7)

    #pragma unroll
    for (int m = 1; m < 64; m <<= 1) {
        MRG(0, m) MRG(1, m) MRG(2, m) MRG(3, m)
        MRG(4, m) MRG(5, m) MRG(6, m) MRG(7, m)
    }

    DENS(0) DENS(1) DENS(2) DENS(3) DENS(4) DENS(5) DENS(6) DENS(7)
    if (lane == 0) {
        int db = w << 3;
        dens[db + 0] = d0; dens[db + 1] = d1; dens[db + 2] = d2; dens[db + 3] = d3;
        dens[db + 4] = d4; dens[db + 5] = d5; dens[db + 6] = d6; dens[db + 7] = d7;
    }
    __syncthreads();

    // ---- epilogue: 64 rows x 128 cols; thread -> (row, 16 cols); C from ws
    //      (L1/L2-resident broadcast, no LDS conflicts) ----
    {
        int r = tid >> 3;              // 0..63
        int cb = (tid & 7) << 2;       // float4-block base (x4 floats = col/4)
        int m = (g << 6) + r;
        float4 p = lp4s[m & 7][m >> 3];
        float cx = ws[WS_CENT + 4 * b + 0];
        float cy = ws[WS_CENT + 4 * b + 1];
        float cz = ws[WS_CENT + 4 * b + 2];
        float rx = p.x - cx, ry = p.y - cy, rz = p.z - cz;
        float cd = sqrtf(fmaf(rx, rx, fmaf(ry, ry, rz * rz)));
        float ld = dens[r];
        const float4* Cg = (const float4*)(ws + WS_COEF);  // 6 rows x 32 float4
        float4* orow = (float4*)(out + ((size_t)b * NPTS + m) * 128);
        #pragma unroll
        for (int h = 0; h < 4; ++h) {
            int ob = cb + h;
            float4 A0 = Cg[0 * 32 + ob];
            float4 A1 = Cg[1 * 32 + ob];
            float4 A2 = Cg[2 * 32 + ob];
            float4 VD = Cg[3 * 32 + ob];
            float4 VL = Cg[4 * 32 + ob];
            float4 BE = Cg[5 * 32 + ob];
            float4 rv;
            rv.x = fmaf(rx, A0.x, fmaf(ry, A1.x, fmaf(rz, A2.x, fmaf(cd, VD.x, fmaf(ld, VL.x, BE.x)))));
            rv.y = fmaf(rx, A0.y, fmaf(ry, A1.y, fmaf(rz, A2.y, fmaf(cd, VD.y, fmaf(ld, VL.y, BE.y)))));
            rv.z = fmaf(rx, A0.z, fmaf(ry, A1.z, fmaf(rz, A2.z, fmaf(cd, VD.z, fmaf(ld, VL.z, BE.z)))));
            rv.w = fmaf(rx, A0.w, fmaf(ry, A1.w, fmaf(rz, A2.w, fmaf(cd, VD.w, fmaf(ld, VL.w, BE.w)))));
            orow[ob] = rv;
        }
    }
}

extern "C" void kernel_launch(void* const* d_in, const int* in_sizes, int n_in,
                              void* d_out, int out_size, void* d_ws, size_t ws_size,
                              hipStream_t stream) {
    const float* pts    = (const float*)d_in[0];
    const float* W_rel  = (const float*)d_in[1];
    const float* b_rel  = (const float*)d_in[2];
    const float* W_dist = (const float*)d_in[3];
    const float* b_dist = (const float*)d_in[4];
    const float* W_dens = (const float*)d_in[5];
    const float* b_dens = (const float*)d_in[6];
    const float* W_out  = (const float*)d_in[7];
    const float* b_out  = (const float*)d_in[8];
    float* out = (float*)d_out;
    float* ws  = (float*)d_ws;

    hipLaunchKernelGGL(prep_kernel, dim3(NBATCH + 1), dim3(256), 0, stream,
                       pts, W_rel, b_rel, W_dist, b_dist, W_dens, b_dens, W_out, b_out, ws);
    hipLaunchKernelGGL(density_out_kernel, dim3(NBATCH * 64), dim3(512), 0, stream,
                       pts, ws, out);
}